// Round 1
// baseline (574.143 us; speedup 1.0000x reference)
//
#include <hip/hip_runtime.h>
#include <math.h>

// ---- problem constants ----
#define TB        256           // threads per block (main kernel)
#define NPOS      131072        // B*H*W positions
#define KCODES    512
#define DIM       64
#define HW        4096          // H*W
#define LOSS_OFF  8388608ull
#define ENC_OFF   8388609ull
#define PERP_OFF  75497473ull

__device__ __forceinline__ float tree8(float r0, float r1, float r2, float r3,
                                       float r4, float r5, float r6, float r7) {
    // numpy pairwise combine: ((r0+r1)+(r2+r3)) + ((r4+r5)+(r6+r7))
    return __fadd_rn(__fadd_rn(__fadd_rn(r0, r1), __fadd_rn(r2, r3)),
                     __fadd_rn(__fadd_rn(r4, r5), __fadd_rn(r6, r7)));
}

// Prep: ww[k] = sum(w[k]^2) in numpy pairwise order; zero counts + loss accumulator.
extern "C" __global__ __launch_bounds__(512)
void vq_prep(const float* __restrict__ w, float* __restrict__ ww,
             int* __restrict__ counts, float* __restrict__ lossAcc)
{
    const int k = threadIdx.x;                 // 512 threads
    const float* wk = w + k * DIM;
    float r[8];
    #pragma unroll
    for (int i = 0; i < 8; ++i) {
        #pragma unroll
        for (int j = 0; j < 8; ++j) {
            float v = wk[i * 8 + j];
            float pp = __fmul_rn(v, v);
            r[j] = (i == 0) ? pp : __fadd_rn(r[j], pp);
        }
    }
    ww[k] = tree8(r[0], r[1], r[2], r[3], r[4], r[5], r[6], r[7]);
    counts[k] = 0;
    if (k == 0) *lossAcc = 0.0f;
}

// Main: per-position argmin over 512 codes + quantized write + one-hot write
// (zero-fill interleaved into the k-loop) + loss partial + histogram.
extern "C" __global__ __launch_bounds__(TB)
void vq_main(const float* __restrict__ x, const float* __restrict__ w,
             const float* __restrict__ ww, float* __restrict__ out,
             int* __restrict__ counts, float* __restrict__ lossAcc)
{
    __shared__ int   hcount[KCODES];
    __shared__ float lred[TB];

    const int tid = threadIdx.x;
    const int n   = blockIdx.x * TB + tid;     // position index (blocks never straddle b)
    const int b   = n >> 12;                   // n / 4096
    const int hw  = n & 4095;

    hcount[tid]       = 0;
    hcount[tid + TB]  = 0;

    // ---- load x (strided: channel stride = HW), build 2x and A = sum(x^2)
    // A replicates numpy pairwise_sum(n=64): r[j] = p[j]+p[8+j]+...+p[56+j], then tree.
    const float* xp = x + ((size_t)b * DIM) * HW + hw;
    float xd2[DIM];
    float r[8];
    #pragma unroll
    for (int i = 0; i < 8; ++i) {
        #pragma unroll
        for (int j = 0; j < 8; ++j) {
            const int d = i * 8 + j;
            float v = xp[(size_t)d * HW];
            xd2[d] = v + v;                     // exact
            float pp = __fmul_rn(v, v);
            r[j] = (i == 0) ? pp : __fadd_rn(r[j], pp);
        }
    }
    const float A = tree8(r[0], r[1], r[2], r[3], r[4], r[5], r[6], r[7]);

    // ---- argmin over codes; interleave zero-fill of this block's encodings slice
    float best = INFINITY;
    int   bestk = 0;
    float* zs = out + ENC_OFF + (size_t)blockIdx.x * (TB * KCODES) + tid;

    #pragma unroll 2
    for (int k = 0; k < KCODES; ++k) {
        const float* wk = w + k * DIM;          // wave-uniform -> s_load path
        float s[8];
        #pragma unroll
        for (int j = 0; j < 8; ++j) s[j] = 0.0f;
        #pragma unroll
        for (int i = 0; i < 8; ++i) {
            #pragma unroll
            for (int j = 0; j < 8; ++j) {
                s[j] = __fmaf_rn(xd2[i * 8 + j], wk[i * 8 + j], s[j]);
            }
        }
        float dot  = tree8(s[0], s[1], s[2], s[3], s[4], s[5], s[6], s[7]);
        float t    = __fadd_rn(A, ww[k]);       // (||x||^2 + ||w_k||^2), ref order
        float dist = __fadd_rn(t, -dot);        // minus 2*x.w  (== __fsub_rn)
        if (dist < best) { best = dist; bestk = k; }

        zs[0] = 0.0f;                           // zero-fill, drains async behind FMAs
        zs += TB;
    }

    __syncthreads();   // drains all zero stores (compiler emits vmcnt(0) before barrier)

    // one-hot "1" lands after the zeros
    out[ENC_OFF + (size_t)n * KCODES + bestk] = 1.0f;

    atomicAdd(&hcount[bestk], 1);

    // ---- quantized output (transposed back) + SSE partial
    const float4* wrow = reinterpret_cast<const float4*>(w + bestk * DIM);
    float* qo = out + ((size_t)b * DIM) * HW + hw;
    float sse = 0.0f;
    #pragma unroll
    for (int i = 0; i < 16; ++i) {
        float4 q = wrow[i];
        const int d = i * 4;
        qo[(size_t)(d + 0) * HW] = q.x;
        qo[(size_t)(d + 1) * HW] = q.y;
        qo[(size_t)(d + 2) * HW] = q.z;
        qo[(size_t)(d + 3) * HW] = q.w;
        float e0 = q.x - 0.5f * xd2[d + 0]; sse = __fmaf_rn(e0, e0, sse);
        float e1 = q.y - 0.5f * xd2[d + 1]; sse = __fmaf_rn(e1, e1, sse);
        float e2 = q.z - 0.5f * xd2[d + 2]; sse = __fmaf_rn(e2, e2, sse);
        float e3 = q.w - 0.5f * xd2[d + 3]; sse = __fmaf_rn(e3, e3, sse);
    }
    lred[tid] = sse;
    __syncthreads();

    // histogram drain
    {
        int c0 = hcount[tid];       if (c0) atomicAdd(&counts[tid], c0);
        int c1 = hcount[tid + TB];  if (c1) atomicAdd(&counts[tid + TB], c1);
    }

    // block loss reduction
    for (int s = TB / 2; s > 0; s >>= 1) {
        if (tid < s) lred[tid] += lred[tid + s];
        __syncthreads();
    }
    if (tid == 0) atomicAdd(lossAcc, lred[0]);
}

// Finalize: loss scalar + perplexity from histogram.
extern "C" __global__ __launch_bounds__(512)
void vq_finalize(const int* __restrict__ counts, const float* __restrict__ lossAcc,
                 float* __restrict__ out)
{
    __shared__ double sred[KCODES];
    const int t = threadIdx.x;                 // 512 threads
    double p = (double)counts[t] * (1.0 / (double)NPOS);
    sred[t] = -p * log(p + 1e-10);
    __syncthreads();
    for (int s = KCODES / 2; s > 0; s >>= 1) {
        if (t < s) sred[t] += sred[t + s];
        __syncthreads();
    }
    if (t == 0) {
        out[PERP_OFF] = (float)exp(sred[0]);
        out[LOSS_OFF] = 1.25f * (lossAcc[0] / 8388608.0f);
    }
}

extern "C" void kernel_launch(void* const* d_in, const int* in_sizes, int n_in,
                              void* d_out, int out_size, void* d_ws, size_t ws_size,
                              hipStream_t stream)
{
    const float* x = (const float*)d_in[0];    // [32,64,64,64] fp32
    const float* w = (const float*)d_in[1];    // [512,64] fp32
    float* out = (float*)d_out;

    float* ww      = (float*)d_ws;                         // 512 floats
    int*   counts  = (int*)((char*)d_ws + 2048);           // 512 ints
    float* lossAcc = (float*)((char*)d_ws + 4096);         // 1 float

    vq_prep<<<1, 512, 0, stream>>>(w, ww, counts, lossAcc);
    vq_main<<<NPOS / TB, TB, 0, stream>>>(x, w, ww, out, counts, lossAcc);
    vq_finalize<<<1, 512, 0, stream>>>(counts, lossAcc, out);
}